// Round 3
// baseline (1620.307 us; speedup 1.0000x reference)
//
#include <hip/hip_runtime.h>

#define T_STEPS 512
#define BATCH   2048
#define DIN     128
#define NH      16
#define COMB    (DIN + NH)
#define G64     64            // 4 gates * 16 outputs

__device__ __forceinline__ float rcpf(float x)  { return __builtin_amdgcn_rcpf(x); }
__device__ __forceinline__ float sigmf(float x) { return rcpf(1.f + __expf(-x)); }
__device__ __forceinline__ float tanhf_(float x){ float e = __expf(2.f * x); return (e - 1.f) * rcpf(e + 1.f); }

// value from lane (k - D) within each 16-lane row; lanes k < D receive 1.0f (mul identity)
template <int D>
__device__ __forceinline__ float scan_shr(float v) {
    int r = __builtin_amdgcn_update_dpp(0x3f800000, __float_as_int(v),
                                        0x110 | D, 0xF, 0xF, false);
    return __int_as_float(r);
}

// ---------------------------------------------------------------------------
// Phase 1: recurrence-independent x-projection.
// zx[row][g*16+k] = sum_j x[row][j] * W[g][k][j]  + b[g][k] + theta[g][k]
// row = t_local*BATCH + b.  Team = 2 waves (one per gate-pair), lane=(k, jc):
// per-lane W footprint = 2 gates * 32 K-slice = 64 VGPRs -> fully register
// resident (this is the spill the old fused kernel was paying for).
// ---------------------------------------------------------------------------
__global__ __launch_bounds__(256, 4) void zx_kernel(
    const float* __restrict__ x,
    const float* __restrict__ Wf, const float* __restrict__ bf,
    const float* __restrict__ Wi, const float* __restrict__ bi,
    const float* __restrict__ Wu, const float* __restrict__ bu,
    const float* __restrict__ Wo, const float* __restrict__ bo,
    const float* __restrict__ thf, const float* __restrict__ thi,
    const float* __restrict__ thu, const float* __restrict__ tho,
    float* __restrict__ zx, int t0, int tc)
{
    const int tid  = threadIdx.x;
    const int lane = tid & 63;
    const int k    = lane & 15;          // gate-output index
    const int jc   = (lane >> 4) & 3;    // K-chunk (4 chunks of 32)
    const int wid  = tid >> 6;           // wave in block 0..3
    const int gp   = wid & 1;            // gate pair: 0 -> {f,i}, 1 -> {u,o}
    const int team = wid >> 1;           // 2 teams per block

    const float* Wg[4] = {Wf, Wi, Wu, Wo};
    const float* bg[4] = {bf, bi, bu, bo};
    const float* tg[4] = {thf, thi, thu, tho};

    float w0[32], w1[32];
    const float* W0 = Wg[gp * 2 + 0] + k * COMB + jc * 32;
    const float* W1 = Wg[gp * 2 + 1] + k * COMB + jc * 32;
#pragma unroll
    for (int j = 0; j < 32; ++j) { w0[j] = W0[j]; w1[j] = W1[j]; }
    const float bt0 = bg[gp * 2 + 0][k] + tg[gp * 2 + 0][k];
    const float bt1 = bg[gp * 2 + 1][k] + tg[gp * 2 + 1][k];

    const long rows  = (long)tc * BATCH;
    const long teams = (long)gridDim.x * 2;
    for (long r = (long)blockIdx.x * 2 + team; r < rows; r += teams) {
        const int tl = (int)(r >> 11);            // BATCH == 2048 == 2^11
        const int b  = (int)(r & (BATCH - 1));
        const float* xp = x + ((size_t)(t0 + tl) * BATCH + b) * DIN + jc * 32;
        float cv[32];
#pragma unroll
        for (int j4 = 0; j4 < 8; ++j4) {
            const float4 v = *(const float4*)(xp + j4 * 4);
            cv[j4 * 4 + 0] = v.x; cv[j4 * 4 + 1] = v.y;
            cv[j4 * 4 + 2] = v.z; cv[j4 * 4 + 3] = v.w;
        }
        float a0 = 0.f, a1 = 0.f;
#pragma unroll
        for (int j = 0; j < 32; ++j) { a0 += cv[j] * w0[j]; a1 += cv[j] * w1[j]; }
        a0 += __shfl_xor(a0, 16, 64); a0 += __shfl_xor(a0, 32, 64);
        a1 += __shfl_xor(a1, 16, 64); a1 += __shfl_xor(a1, 32, 64);
        if (jc == 0) {
            float* zp = zx + (size_t)r * G64 + gp * 32 + k;
            zp[0]  = a0 + bt0;
            zp[16] = a1 + bt1;
        }
    }
}

// ---------------------------------------------------------------------------
// Phase 2: serial recurrence. One wave per batch element, lane = g*16 + k
// (each lane owns exactly one gate output). Per step: zx load (4-deep
// prefetch), 16-FMA h-matmul via v_readlane broadcasts, cos, 4-DPP segmented
// cumprod (one value/lane -> 4 DPP ops total, not 16), branchless activation
// (tanh = 2*sigmoid(2x)-1), 4 ds_bpermute to gather f,i,u,o per k.
// h,c carried across T-chunks through out's hx/cx slots.
// ---------------------------------------------------------------------------
__global__ __launch_bounds__(64, 2) void rec_kernel(
    const float* __restrict__ zx,
    const float* __restrict__ Wf, const float* __restrict__ Wi,
    const float* __restrict__ Wu, const float* __restrict__ Wo,
    float* __restrict__ out, int t0, int tc)
{
    const int lane = threadIdx.x;        // 0..63
    const int k = lane & 15;
    const int g = lane >> 4;
    const int b = blockIdx.x;

    const float* Wg[4] = {Wf, Wi, Wu, Wo};
    float wh[16];
    {
        const float* Wr = Wg[g] + k * COMB + DIN;
#pragma unroll
        for (int kk = 0; kk < 16; ++kk) wh[kk] = Wr[kk];
    }
    // u-gate (g==2) uses tanh(x) = 2*sigmoid(2x) - 1; others sigmoid.
    const float sc  = (g == 2) ? 2.f : 1.f;
    const float off = (g == 2) ? -1.f : 0.f;
    // bpermute byte indices for gathering f,i,u,o of this lane's k
    const int i_f = k * 4, i_i = (16 + k) * 4, i_u = (32 + k) * 4, i_o = (48 + k) * 4;

    const size_t sbase = (size_t)T_STEPS * BATCH * NH;
    float h, c;
    if (t0 == 0) { h = 0.f; c = 0.f; }
    else {       // carry-in from previous chunk (we wrote these slots ourselves)
        h = out[sbase + (size_t)b * NH + k];
        c = out[sbase + (size_t)BATCH * NH + (size_t)b * NH + k];
    }

    const size_t zstr = (size_t)BATCH * G64;
    const float* zrow = zx + (size_t)b * G64 + lane;
    auto zload = [&](int t) -> float {
        const int tt = (t < tc) ? t : tc - 1;    // clamped (tail loads harmless)
        return zrow[(size_t)tt * zstr];
    };

    float* op = out + ((size_t)t0 * BATCH + b) * NH + k;

    auto step = [&](float z) {
        // h-part: z already includes bias+theta (folded in zx_kernel)
        float a0 = z, a1 = 0.f;
#pragma unroll
        for (int kk = 0; kk < 8; ++kk) {
            const float h0 = __int_as_float(__builtin_amdgcn_readlane(__float_as_int(h), kk));
            const float h1 = __int_as_float(__builtin_amdgcn_readlane(__float_as_int(h), kk + 8));
            a0 += h0 * wh[kk];
            a1 += h1 * wh[kk + 8];
        }
        float v = __cosf(a0 + a1);
        v *= scan_shr<1>(v); v *= scan_shr<2>(v); v *= scan_shr<4>(v); v *= scan_shr<8>(v);
        const float e   = __expf(-(v * sc));
        const float s   = rcpf(1.f + e);
        const float act = s * sc + off;
        const int ai = __float_as_int(act);
        const float f  = __int_as_float(__builtin_amdgcn_ds_bpermute(i_f, ai));
        const float i_ = __int_as_float(__builtin_amdgcn_ds_bpermute(i_i, ai));
        const float u  = __int_as_float(__builtin_amdgcn_ds_bpermute(i_u, ai));
        const float o  = __int_as_float(__builtin_amdgcn_ds_bpermute(i_o, ai));
        c = f * c + i_ * u;
        const float e2 = __expf(-2.f * c);
        const float th = (1.f - e2) * rcpf(1.f + e2);
        h = o * th;
        if (g == 0) *op = h;                     // 16 lanes -> one 64B store
        op += (size_t)BATCH * NH;
    };

    // 4-deep prefetch: ~4 steps (~500+ cycles) of load-latency cover
    float za = zload(0), zb = zload(1), zc = zload(2), zd = zload(3);
    for (int tl = 0; tl < tc; tl += 4) {         // all chunk sizes divisible by 4
        step(za); za = zload(tl + 4);
        step(zb); zb = zload(tl + 5);
        step(zc); zc = zload(tl + 6);
        step(zd); zd = zload(tl + 7);
    }

    if (g == 0) {                                // hx, cx (also chunk carry)
        out[sbase + (size_t)b * NH + k] = h;
        out[sbase + (size_t)BATCH * NH + (size_t)b * NH + k] = c;
    }
}

// ---------------------------------------------------------------------------
// Fallback: previous fused kernel (used only if workspace is too small).
// ---------------------------------------------------------------------------
__global__ __launch_bounds__(64, 2) void qlstm_kernel(
    const float* __restrict__ x,
    const float* __restrict__ Wf, const float* __restrict__ bf,
    const float* __restrict__ Wi, const float* __restrict__ bi,
    const float* __restrict__ Wu, const float* __restrict__ bu,
    const float* __restrict__ Wo, const float* __restrict__ bo,
    const float* __restrict__ thf, const float* __restrict__ thi,
    const float* __restrict__ thu, const float* __restrict__ tho,
    float* __restrict__ out)
{
    const int lane = threadIdx.x;
    const int k    = lane & 15;
    const int q    = lane >> 4;
    const int b    = blockIdx.x;

    const float* Wg[4] = {Wf, Wi, Wu, Wo};
    const float* bg[4] = {bf, bi, bu, bo};
    const float* tg[4] = {thf, thi, thu, tho};

    float w[4][32], wh[4][4], bt[4];
#pragma unroll
    for (int g = 0; g < 4; ++g) {
        const float* Wr = Wg[g] + k * COMB;
#pragma unroll
        for (int j = 0; j < 32; ++j) w[g][j] = Wr[q * 32 + j];
#pragma unroll
        for (int kk = 0; kk < 4; ++kk) wh[g][kk] = Wr[DIN + q * 4 + kk];
        bt[g] = bg[g][k] + tg[g][k];
    }

    float h = 0.f, c = 0.f;
    float cvA[32], cvB[32];

    auto xrow = [&](int t) -> const float* {
        return x + ((size_t)t * BATCH + b) * DIN + q * 32;
    };
    auto loadx = [&](float (&cv)[32], const float* p) {
#pragma unroll
        for (int j4 = 0; j4 < 8; ++j4) {
            const float4 v = *(const float4*)(p + j4 * 4);
            cv[j4 * 4 + 0] = v.x; cv[j4 * 4 + 1] = v.y;
            cv[j4 * 4 + 2] = v.z; cv[j4 * 4 + 3] = v.w;
        }
    };

    float* op = out + (size_t)b * NH + k;

    auto step = [&](int t, float (&cv)[32]) {
        float acc[4] = {0.f, 0.f, 0.f, 0.f};
#pragma unroll
        for (int j = 0; j < 32; ++j) {
#pragma unroll
            for (int g = 0; g < 4; ++g) acc[g] += cv[j] * w[g][j];
        }
#pragma unroll
        for (int kk = 0; kk < 4; ++kk) {
            const float hv = __shfl(h, q * 4 + kk, 64);
#pragma unroll
            for (int g = 0; g < 4; ++g) acc[g] += hv * wh[g][kk];
        }
#pragma unroll
        for (int g = 0; g < 4; ++g) {
            acc[g] += __shfl_xor(acc[g], 16, 64);
            acc[g] += __shfl_xor(acc[g], 32, 64);
            acc[g] = __cosf(acc[g] + bt[g]);
        }
#pragma unroll
        for (int g = 0; g < 4; ++g) {
            acc[g] *= scan_shr<1>(acc[g]);
            acc[g] *= scan_shr<2>(acc[g]);
            acc[g] *= scan_shr<4>(acc[g]);
            acc[g] *= scan_shr<8>(acc[g]);
        }
        const float f  = sigmf(acc[0]);
        const float i_ = sigmf(acc[1]);
        const float u  = tanhf_(acc[2]);
        const float o  = sigmf(acc[3]);
        c = f * c + i_ * u;
        h = o * tanhf_(c);
        if (q == 0) *op = h;
        op += (size_t)BATCH * NH;
    };

    loadx(cvA, xrow(0));
    for (int t = 0; t < T_STEPS; t += 2) {
        loadx(cvB, xrow(t + 1));
        step(t, cvA);
        const int tn = (t + 2 < T_STEPS) ? t + 2 : T_STEPS - 1;
        loadx(cvA, xrow(tn));
        step(t + 1, cvB);
    }

    if (q == 0) {
        const size_t base = (size_t)T_STEPS * BATCH * NH;
        out[base + (size_t)b * NH + k] = h;
        out[base + (size_t)BATCH * NH + (size_t)b * NH + k] = c;
    }
}

extern "C" void kernel_launch(void* const* d_in, const int* in_sizes, int n_in,
                              void* d_out, int out_size, void* d_ws, size_t ws_size,
                              hipStream_t stream) {
    const float* x   = (const float*)d_in[0];
    const float* Wf  = (const float*)d_in[1];
    const float* bf  = (const float*)d_in[2];
    const float* Wi  = (const float*)d_in[3];
    const float* bi  = (const float*)d_in[4];
    const float* Wu  = (const float*)d_in[5];
    const float* bu  = (const float*)d_in[6];
    const float* Wo  = (const float*)d_in[7];
    const float* bo  = (const float*)d_in[8];
    const float* thf = (const float*)d_in[9];
    const float* thi = (const float*)d_in[10];
    const float* thu = (const float*)d_in[11];
    const float* tho = (const float*)d_in[12];
    float* out = (float*)d_out;

    // largest T-chunk whose zx slab fits in the workspace (512 -> 256 MiB)
    int Tc = 0;
    const int cand[7] = {512, 256, 128, 64, 32, 16, 8};
    for (int i = 0; i < 7; ++i) {
        if (d_ws && (size_t)cand[i] * BATCH * G64 * sizeof(float) <= ws_size) {
            Tc = cand[i];
            break;
        }
    }
    if (Tc == 0) {   // no usable workspace: previous fused kernel
        qlstm_kernel<<<dim3(BATCH), dim3(64), 0, stream>>>(
            x, Wf, bf, Wi, bi, Wu, bu, Wo, bo, thf, thi, thu, tho, out);
        return;
    }

    float* zx = (float*)d_ws;
    for (int t0 = 0; t0 < T_STEPS; t0 += Tc) {
        const int tc = (T_STEPS - t0 < Tc) ? (T_STEPS - t0) : Tc;
        zx_kernel<<<dim3(2048), dim3(256), 0, stream>>>(
            x, Wf, bf, Wi, bi, Wu, bu, Wo, bo, thf, thi, thu, tho, zx, t0, tc);
        rec_kernel<<<dim3(BATCH), dim3(64), 0, stream>>>(
            zx, Wf, Wi, Wu, Wo, out, t0, tc);
    }
}

// Round 6
// 1497.962 us; speedup vs baseline: 1.0817x; 1.0817x over previous
//
#include <hip/hip_runtime.h>

#define T_STEPS 512
#define BATCH   2048
#define DIN     128
#define NH      16
#define COMB    (DIN + NH)
#define G64     64            // 4 gates * 16 outputs

__device__ __forceinline__ float rcpf(float x)  { return __builtin_amdgcn_rcpf(x); }
__device__ __forceinline__ float sigmf(float x) { return rcpf(1.f + __expf(-x)); }
__device__ __forceinline__ float tanhf_(float x){ float e = __expf(2.f * x); return (e - 1.f) * rcpf(e + 1.f); }

// value from lane (k - D) within each 16-lane row; lanes k < D receive 1.0f (mul identity)
template <int D>
__device__ __forceinline__ float scan_shr(float v) {
    int r = __builtin_amdgcn_update_dpp(0x3f800000, __float_as_int(v),
                                        0x110 | D, 0xF, 0xF, false);
    return __int_as_float(r);
}

// ---------------------------------------------------------------------------
// Phase 1: recurrence-independent x-projection.
// zx[b][tl][g*16+k] = sum_j x[t0+tl][b][j] * W[g][k][j] + b[g][k] + theta[g][k]
// (note [b][t] layout: rec_kernel then reads a SEQUENTIAL 256B/step stream).
// Team = 2 waves (one per gate-pair), lane=(k, jc).
// launch_bounds(256,2): 256-VGPR cap so w0/w1 + double-buffered cv stay
// register-resident (the (256,4)=128-cap forced weight rematerialization:
// VGPR=48, 874us, 35% VALUBusy — latency-bound on in-loop weight reloads).
// ---------------------------------------------------------------------------
__global__ __launch_bounds__(256, 2) void zx_kernel(
    const float* __restrict__ x,
    const float* __restrict__ Wf, const float* __restrict__ bf,
    const float* __restrict__ Wi, const float* __restrict__ bi,
    const float* __restrict__ Wu, const float* __restrict__ bu,
    const float* __restrict__ Wo, const float* __restrict__ bo,
    const float* __restrict__ thf, const float* __restrict__ thi,
    const float* __restrict__ thu, const float* __restrict__ tho,
    float* __restrict__ zx, int t0, int tc)
{
    const int tid  = threadIdx.x;
    const int lane = tid & 63;
    const int k    = lane & 15;          // gate-output index
    const int jc   = (lane >> 4) & 3;    // K-chunk (4 chunks of 32)
    const int wid  = tid >> 6;           // wave in block 0..3
    const int gp   = wid & 1;            // gate pair: 0 -> {f,i}, 1 -> {u,o}
    const long team = ((long)blockIdx.x << 1) | (wid >> 1);

    const float* Wg[4] = {Wf, Wi, Wu, Wo};
    const float* bg[4] = {bf, bi, bu, bo};
    const float* tg[4] = {thf, thi, thu, tho};

    float w0[32], w1[32];
    const float* W0 = Wg[gp * 2 + 0] + k * COMB + jc * 32;
    const float* W1 = Wg[gp * 2 + 1] + k * COMB + jc * 32;
#pragma unroll
    for (int j = 0; j < 32; ++j) { w0[j] = W0[j]; w1[j] = W1[j]; }
    const float bt0 = bg[gp * 2 + 0][k] + tg[gp * 2 + 0][k];
    const float bt1 = bg[gp * 2 + 1][k] + tg[gp * 2 + 1][k];

    const long rows   = (long)tc * BATCH;
    const long stride = (long)gridDim.x * 2;

    // row r == tl*BATCH + b, so x-row address is linear in r
    auto xptr = [&](long r) -> const float* {
        return x + ((size_t)t0 * BATCH + (size_t)r) * DIN + jc * 32;
    };
    auto loadx = [&](float (&cv)[32], const float* p) {
#pragma unroll
        for (int j4 = 0; j4 < 8; ++j4) {
            const float4 v = *(const float4*)(p + j4 * 4);
            cv[j4 * 4 + 0] = v.x; cv[j4 * 4 + 1] = v.y;
            cv[j4 * 4 + 2] = v.z; cv[j4 * 4 + 3] = v.w;
        }
    };
    auto compute_store = [&](long r, const float (&cv)[32]) {
        // 4 independent 16-deep FMA chains (issue-bound, not latency-bound)
        float a0 = 0.f, a1 = 0.f, b0 = 0.f, b1 = 0.f;
#pragma unroll
        for (int j = 0; j < 16; ++j) {
            a0 += cv[j] * w0[j];       a1 += cv[j + 16] * w0[j + 16];
            b0 += cv[j] * w1[j];       b1 += cv[j + 16] * w1[j + 16];
        }
        float a = a0 + a1, bb = b0 + b1;
        a  += __shfl_xor(a, 16, 64);  a  += __shfl_xor(a, 32, 64);
        bb += __shfl_xor(bb, 16, 64); bb += __shfl_xor(bb, 32, 64);
        if (jc == 0) {
            const int tl = (int)(r >> 11);            // BATCH == 2048 == 2^11
            const int b  = (int)(r & (BATCH - 1));
            float* zp = zx + ((size_t)b * tc + tl) * G64 + gp * 32 + k;
            zp[0]  = a  + bt0;
            zp[16] = bb + bt1;
        }
    };

    float cvA[32], cvB[32];
    long r = team;
    if (r >= rows) return;
    loadx(cvA, xptr(r));
    for (; r < rows; r += 2 * stride) {
        const long r1 = r + stride;
        loadx(cvB, xptr(r1 < rows ? r1 : r));         // prefetch (clamped)
        compute_store(r, cvA);
        const long r2 = r + 2 * stride;
        loadx(cvA, xptr(r2 < rows ? r2 : r));         // prefetch (clamped)
        if (r1 < rows) compute_store(r1, cvB);
    }
}

// ---------------------------------------------------------------------------
// Phase 2: serial recurrence. One wave per batch element, lane = g*16 + k.
// zx is [b][t][64]: per-step load is one sequential 256B line per wave.
// ---------------------------------------------------------------------------
__global__ __launch_bounds__(64, 2) void rec_kernel(
    const float* __restrict__ zx,
    const float* __restrict__ Wf, const float* __restrict__ Wi,
    const float* __restrict__ Wu, const float* __restrict__ Wo,
    float* __restrict__ out, int t0, int tc)
{
    const int lane = threadIdx.x;        // 0..63
    const int k = lane & 15;
    const int g = lane >> 4;
    const int b = blockIdx.x;

    const float* Wg[4] = {Wf, Wi, Wu, Wo};
    float wh[16];
    {
        const float* Wr = Wg[g] + k * COMB + DIN;
#pragma unroll
        for (int kk = 0; kk < 16; ++kk) wh[kk] = Wr[kk];
    }
    // u-gate (g==2) uses tanh(x) = 2*sigmoid(2x) - 1; others sigmoid.
    const float sc  = (g == 2) ? 2.f : 1.f;
    const float off = (g == 2) ? -1.f : 0.f;
    // bpermute byte indices for gathering f,i,u,o of this lane's k
    const int i_f = k * 4, i_i = (16 + k) * 4, i_u = (32 + k) * 4, i_o = (48 + k) * 4;

    const size_t sbase = (size_t)T_STEPS * BATCH * NH;
    float h, c;
    if (t0 == 0) { h = 0.f; c = 0.f; }
    else {       // carry-in from previous chunk (we wrote these slots ourselves)
        h = out[sbase + (size_t)b * NH + k];
        c = out[sbase + (size_t)BATCH * NH + (size_t)b * NH + k];
    }

    const float* zrow = zx + (size_t)b * tc * G64 + lane;
    auto zload = [&](int t) -> float {
        const int tt = (t < tc) ? t : tc - 1;    // clamped (tail loads harmless)
        return zrow[(size_t)tt * G64];
    };

    float* op = out + ((size_t)t0 * BATCH + b) * NH + k;

    auto step = [&](float z) {
        // h-part: z already includes bias+theta (folded in zx_kernel)
        float a0 = z, a1 = 0.f;
#pragma unroll
        for (int kk = 0; kk < 8; ++kk) {
            const float h0 = __int_as_float(__builtin_amdgcn_readlane(__float_as_int(h), kk));
            const float h1 = __int_as_float(__builtin_amdgcn_readlane(__float_as_int(h), kk + 8));
            a0 += h0 * wh[kk];
            a1 += h1 * wh[kk + 8];
        }
        float v = __cosf(a0 + a1);
        v *= scan_shr<1>(v); v *= scan_shr<2>(v); v *= scan_shr<4>(v); v *= scan_shr<8>(v);
        const float e   = __expf(-(v * sc));
        const float s   = rcpf(1.f + e);
        const float act = s * sc + off;
        const int ai = __float_as_int(act);
        const float f  = __int_as_float(__builtin_amdgcn_ds_bpermute(i_f, ai));
        const float i_ = __int_as_float(__builtin_amdgcn_ds_bpermute(i_i, ai));
        const float u  = __int_as_float(__builtin_amdgcn_ds_bpermute(i_u, ai));
        const float o  = __int_as_float(__builtin_amdgcn_ds_bpermute(i_o, ai));
        c = f * c + i_ * u;
        const float e2 = __expf(-2.f * c);
        const float th = (1.f - e2) * rcpf(1.f + e2);
        h = o * th;
        if (g == 0) *op = h;                     // 16 lanes -> one 64B store
        op += (size_t)BATCH * NH;
    };

    // 4-deep prefetch: ~4 steps of load-latency cover (stream is sequential now)
    float za = zload(0), zb = zload(1), zc = zload(2), zd = zload(3);
    for (int tl = 0; tl < tc; tl += 4) {         // all chunk sizes divisible by 4
        step(za); za = zload(tl + 4);
        step(zb); zb = zload(tl + 5);
        step(zc); zc = zload(tl + 6);
        step(zd); zd = zload(tl + 7);
    }

    if (g == 0) {                                // hx, cx (also chunk carry)
        out[sbase + (size_t)b * NH + k] = h;
        out[sbase + (size_t)BATCH * NH + (size_t)b * NH + k] = c;
    }
}

// ---------------------------------------------------------------------------
// Fallback: original fused kernel (used only if workspace is too small).
// ---------------------------------------------------------------------------
__global__ __launch_bounds__(64, 2) void qlstm_kernel(
    const float* __restrict__ x,
    const float* __restrict__ Wf, const float* __restrict__ bf,
    const float* __restrict__ Wi, const float* __restrict__ bi,
    const float* __restrict__ Wu, const float* __restrict__ bu,
    const float* __restrict__ Wo, const float* __restrict__ bo,
    const float* __restrict__ thf, const float* __restrict__ thi,
    const float* __restrict__ thu, const float* __restrict__ tho,
    float* __restrict__ out)
{
    const int lane = threadIdx.x;
    const int k    = lane & 15;
    const int q    = lane >> 4;
    const int b    = blockIdx.x;

    const float* Wg[4] = {Wf, Wi, Wu, Wo};
    const float* bg[4] = {bf, bi, bu, bo};
    const float* tg[4] = {thf, thi, thu, tho};

    float w[4][32], wh[4][4], bt[4];
#pragma unroll
    for (int g = 0; g < 4; ++g) {
        const float* Wr = Wg[g] + k * COMB;
#pragma unroll
        for (int j = 0; j < 32; ++j) w[g][j] = Wr[q * 32 + j];
#pragma unroll
        for (int kk = 0; kk < 4; ++kk) wh[g][kk] = Wr[DIN + q * 4 + kk];
        bt[g] = bg[g][k] + tg[g][k];
    }

    float h = 0.f, c = 0.f;
    float cvA[32], cvB[32];

    auto xrow = [&](int t) -> const float* {
        return x + ((size_t)t * BATCH + b) * DIN + q * 32;
    };
    auto loadx = [&](float (&cv)[32], const float* p) {
#pragma unroll
        for (int j4 = 0; j4 < 8; ++j4) {
            const float4 v = *(const float4*)(p + j4 * 4);
            cv[j4 * 4 + 0] = v.x; cv[j4 * 4 + 1] = v.y;
            cv[j4 * 4 + 2] = v.z; cv[j4 * 4 + 3] = v.w;
        }
    };

    float* op = out + (size_t)b * NH + k;

    auto step = [&](int t, float (&cv)[32]) {
        float acc[4] = {0.f, 0.f, 0.f, 0.f};
#pragma unroll
        for (int j = 0; j < 32; ++j) {
#pragma unroll
            for (int g = 0; g < 4; ++g) acc[g] += cv[j] * w[g][j];
        }
#pragma unroll
        for (int kk = 0; kk < 4; ++kk) {
            const float hv = __shfl(h, q * 4 + kk, 64);
#pragma unroll
            for (int g = 0; g < 4; ++g) acc[g] += hv * wh[g][kk];
        }
#pragma unroll
        for (int g = 0; g < 4; ++g) {
            acc[g] += __shfl_xor(acc[g], 16, 64);
            acc[g] += __shfl_xor(acc[g], 32, 64);
            acc[g] = __cosf(acc[g] + bt[g]);
        }
#pragma unroll
        for (int g = 0; g < 4; ++g) {
            acc[g] *= scan_shr<1>(acc[g]);
            acc[g] *= scan_shr<2>(acc[g]);
            acc[g] *= scan_shr<4>(acc[g]);
            acc[g] *= scan_shr<8>(acc[g]);
        }
        const float f  = sigmf(acc[0]);
        const float i_ = sigmf(acc[1]);
        const float u  = tanhf_(acc[2]);
        const float o  = sigmf(acc[3]);
        c = f * c + i_ * u;
        h = o * tanhf_(c);
        if (q == 0) *op = h;
        op += (size_t)BATCH * NH;
    };

    loadx(cvA, xrow(0));
    for (int t = 0; t < T_STEPS; t += 2) {
        loadx(cvB, xrow(t + 1));
        step(t, cvA);
        const int tn = (t + 2 < T_STEPS) ? t + 2 : T_STEPS - 1;
        loadx(cvA, xrow(tn));
        step(t + 1, cvB);
    }

    if (q == 0) {
        const size_t base = (size_t)T_STEPS * BATCH * NH;
        out[base + (size_t)b * NH + k] = h;
        out[base + (size_t)BATCH * NH + (size_t)b * NH + k] = c;
    }
}

extern "C" void kernel_launch(void* const* d_in, const int* in_sizes, int n_in,
                              void* d_out, int out_size, void* d_ws, size_t ws_size,
                              hipStream_t stream) {
    const float* x   = (const float*)d_in[0];
    const float* Wf  = (const float*)d_in[1];
    const float* bf  = (const float*)d_in[2];
    const float* Wi  = (const float*)d_in[3];
    const float* bi  = (const float*)d_in[4];
    const float* Wu  = (const float*)d_in[5];
    const float* bu  = (const float*)d_in[6];
    const float* Wo  = (const float*)d_in[7];
    const float* bo  = (const float*)d_in[8];
    const float* thf = (const float*)d_in[9];
    const float* thi = (const float*)d_in[10];
    const float* thu = (const float*)d_in[11];
    const float* tho = (const float*)d_in[12];
    float* out = (float*)d_out;

    // largest T-chunk whose zx slab fits in the workspace (512 -> 256 MiB)
    int Tc = 0;
    const int cand[7] = {512, 256, 128, 64, 32, 16, 8};
    for (int i = 0; i < 7; ++i) {
        if (d_ws && (size_t)cand[i] * BATCH * G64 * sizeof(float) <= ws_size) {
            Tc = cand[i];
            break;
        }
    }
    if (Tc == 0) {   // no usable workspace: fused fallback
        qlstm_kernel<<<dim3(BATCH), dim3(64), 0, stream>>>(
            x, Wf, bf, Wi, bi, Wu, bu, Wo, bo, thf, thi, thu, tho, out);
        return;
    }

    float* zx = (float*)d_ws;
    for (int t0 = 0; t0 < T_STEPS; t0 += Tc) {
        const int tc = (T_STEPS - t0 < Tc) ? (T_STEPS - t0) : Tc;
        zx_kernel<<<dim3(2048), dim3(256), 0, stream>>>(
            x, Wf, bf, Wi, bi, Wu, bu, Wo, bo, thf, thi, thu, tho, zx, t0, tc);
        rec_kernel<<<dim3(BATCH), dim3(64), 0, stream>>>(
            zx, Wf, Wi, Wu, Wo, out, t0, tc);
    }
}

// Round 7
// 1448.821 us; speedup vs baseline: 1.1184x; 1.0339x over previous
//
#include <hip/hip_runtime.h>

#define T_STEPS 512
#define BATCH   2048
#define DIN     128
#define NH      16
#define COMB    (DIN + NH)
#define G64     64            // 4 gates * 16 outputs

__device__ __forceinline__ float rcpf(float x)  { return __builtin_amdgcn_rcpf(x); }
__device__ __forceinline__ float sigmf(float x) { return rcpf(1.f + __expf(-x)); }
__device__ __forceinline__ float tanhf_(float x){ float e = __expf(2.f * x); return (e - 1.f) * rcpf(e + 1.f); }
__device__ __forceinline__ float rl(float v, int l) {
    return __int_as_float(__builtin_amdgcn_readlane(__float_as_int(v), l));
}

// value from lane (k - D) within each 16-lane row; lanes k < D receive 1.0f (mul identity)
template <int D>
__device__ __forceinline__ float scan_shr(float v) {
    int r = __builtin_amdgcn_update_dpp(0x3f800000, __float_as_int(v),
                                        0x110 | D, 0xF, 0xF, false);
    return __int_as_float(r);
}

// ---------------------------------------------------------------------------
// Phase 1: x-projection. zx[b][tl][g*16+k] layout (sequential rec reads).
// Weights are PINNED into VGPRs via empty-asm: round-3/6 showed the allocator
// rematerializes the 64 weight loads in-loop at ANY launch_bounds cap
// (VGPR=48@(256,4), VGPR=72@(256,2) — both latency-bound, 874/743us).
// asm "+v" marks each element modified -> cannot be rematerialized.
// ---------------------------------------------------------------------------
__global__ __launch_bounds__(256, 2) void zx_kernel(
    const float* __restrict__ x,
    const float* __restrict__ Wf, const float* __restrict__ bf,
    const float* __restrict__ Wi, const float* __restrict__ bi,
    const float* __restrict__ Wu, const float* __restrict__ bu,
    const float* __restrict__ Wo, const float* __restrict__ bo,
    const float* __restrict__ thf, const float* __restrict__ thi,
    const float* __restrict__ thu, const float* __restrict__ tho,
    float* __restrict__ zx, int t0, int tc)
{
    const int tid  = threadIdx.x;
    const int lane = tid & 63;
    const int k    = lane & 15;          // gate-output index
    const int jc   = (lane >> 4) & 3;    // K-chunk (4 chunks of 32)
    const int wid  = tid >> 6;           // wave in block 0..3
    const int gp   = wid & 1;            // gate pair: 0 -> {f,i}, 1 -> {u,o}
    const long team = ((long)blockIdx.x << 1) | (wid >> 1);

    const float* Wg[4] = {Wf, Wi, Wu, Wo};
    const float* bg[4] = {bf, bi, bu, bo};
    const float* tg[4] = {thf, thi, thu, tho};

    float w0[32], w1[32];
    {
        const float* W0 = Wg[gp * 2 + 0] + k * COMB + jc * 32;   // 16B-aligned
        const float* W1 = Wg[gp * 2 + 1] + k * COMB + jc * 32;
#pragma unroll
        for (int j4 = 0; j4 < 8; ++j4) {
            const float4 v0 = *(const float4*)(W0 + j4 * 4);
            const float4 v1 = *(const float4*)(W1 + j4 * 4);
            w0[j4*4+0] = v0.x; w0[j4*4+1] = v0.y; w0[j4*4+2] = v0.z; w0[j4*4+3] = v0.w;
            w1[j4*4+0] = v1.x; w1[j4*4+1] = v1.y; w1[j4*4+2] = v1.z; w1[j4*4+3] = v1.w;
        }
    }
#pragma unroll
    for (int j = 0; j < 32; ++j) {       // force register residency
        asm volatile("" : "+v"(w0[j]));
        asm volatile("" : "+v"(w1[j]));
    }
    const float bt0 = bg[gp * 2 + 0][k] + tg[gp * 2 + 0][k];
    const float bt1 = bg[gp * 2 + 1][k] + tg[gp * 2 + 1][k];

    const long rows   = (long)tc * BATCH;
    const long stride = (long)gridDim.x * 2;

    // row r == tl*BATCH + b, so x-row address is linear in r
    auto xptr = [&](long r) -> const float* {
        return x + ((size_t)t0 * BATCH + (size_t)r) * DIN + jc * 32;
    };
    auto loadx = [&](float (&cv)[32], const float* p) {
#pragma unroll
        for (int j4 = 0; j4 < 8; ++j4) {
            const float4 v = *(const float4*)(p + j4 * 4);
            cv[j4 * 4 + 0] = v.x; cv[j4 * 4 + 1] = v.y;
            cv[j4 * 4 + 2] = v.z; cv[j4 * 4 + 3] = v.w;
        }
    };
    auto compute_store = [&](long r, const float (&cv)[32]) {
        float a0 = 0.f, a1 = 0.f, b0 = 0.f, b1 = 0.f;
#pragma unroll
        for (int j = 0; j < 16; ++j) {
            a0 += cv[j] * w0[j];       a1 += cv[j + 16] * w0[j + 16];
            b0 += cv[j] * w1[j];       b1 += cv[j + 16] * w1[j + 16];
        }
        float a = a0 + a1, bb = b0 + b1;
        a  += __shfl_xor(a, 16, 64);  a  += __shfl_xor(a, 32, 64);
        bb += __shfl_xor(bb, 16, 64); bb += __shfl_xor(bb, 32, 64);
        if (jc == 0) {
            const int tl = (int)(r >> 11);            // BATCH == 2048 == 2^11
            const int b  = (int)(r & (BATCH - 1));
            float* zp = zx + ((size_t)b * tc + tl) * G64 + gp * 32 + k;
            zp[0]  = a  + bt0;
            zp[16] = bb + bt1;
        }
    };

    float cvA[32], cvB[32];
    long r = team;
    if (r >= rows) return;
    loadx(cvA, xptr(r));
    for (; r < rows; r += 2 * stride) {
        const long r1 = r + stride;
        loadx(cvB, xptr(r1 < rows ? r1 : r));         // prefetch (clamped)
        compute_store(r, cvA);
        const long r2 = r + 2 * stride;
        loadx(cvA, xptr(r2 < rows ? r2 : r));         // prefetch (clamped)
        if (r1 < rows) compute_store(r1, cvB);
    }
}

// ---------------------------------------------------------------------------
// Phase 2: serial recurrence. 256-thread blocks, 4 waves = 4 batch elements
// (packs 8 waves/CU into 2 block slots — round-3/6 showed rec at ~750us
// INDEPENDENT of zx memory layout, i.e. not memory-bound: either block
// residency or per-step store/waitcnt serialization). Group-of-4 pipeline:
// 4 loads issued, 4 steps computed with h buffered in regs, 4 stores batched
// -> one vmcnt region per 4 steps instead of per step.
// ---------------------------------------------------------------------------
__global__ __launch_bounds__(256, 2) void rec_kernel(
    const float* __restrict__ zx,
    const float* __restrict__ Wf, const float* __restrict__ Wi,
    const float* __restrict__ Wu, const float* __restrict__ Wo,
    float* __restrict__ out, int t0, int tc)
{
    const int tid  = threadIdx.x;
    const int lane = tid & 63;           // lane within wave
    const int wv   = tid >> 6;           // wave 0..3
    const int k    = lane & 15;
    const int g    = lane >> 4;
    const int b    = (blockIdx.x << 2) | wv;   // batch element

    const float* Wg[4] = {Wf, Wi, Wu, Wo};
    float wh[16];
    {
        const float* Wr = Wg[g] + k * COMB + DIN;
#pragma unroll
        for (int kk = 0; kk < 16; ++kk) wh[kk] = Wr[kk];
    }
#pragma unroll
    for (int kk = 0; kk < 16; ++kk) asm volatile("" : "+v"(wh[kk]));

    // u-gate (g==2) uses tanh(x) = 2*sigmoid(2x) - 1; others sigmoid.
    const float sc  = (g == 2) ? 2.f : 1.f;
    const float off = (g == 2) ? -1.f : 0.f;
    const int i_f = k * 4, i_i = (16 + k) * 4, i_u = (32 + k) * 4, i_o = (48 + k) * 4;

    const size_t sbase = (size_t)T_STEPS * BATCH * NH;
    float h, c;
    if (t0 == 0) { h = 0.f; c = 0.f; }
    else {
        h = out[sbase + (size_t)b * NH + k];
        c = out[sbase + (size_t)BATCH * NH + (size_t)b * NH + k];
    }

    const float* zrow = zx + (size_t)b * tc * G64 + lane;
    auto zld = [&](int t) -> float {
        const int tt = (t < tc) ? t : tc - 1;    // clamped (tail loads harmless)
        return zrow[(size_t)tt * G64];
    };

    const size_t ostr = (size_t)BATCH * NH;
    float* op = out + ((size_t)t0 * BATCH + b) * NH + k;

    auto step = [&](float z) -> float {
        // h-part: 4 independent 4-deep FMA chains off readlane broadcasts
        float a0 = z, a1 = 0.f, a2 = 0.f, a3 = 0.f;
#pragma unroll
        for (int kk = 0; kk < 4; ++kk) {
            a0 += rl(h, kk)      * wh[kk];
            a1 += rl(h, kk + 4)  * wh[kk + 4];
            a2 += rl(h, kk + 8)  * wh[kk + 8];
            a3 += rl(h, kk + 12) * wh[kk + 12];
        }
        float v = __cosf((a0 + a1) + (a2 + a3));
        v *= scan_shr<1>(v); v *= scan_shr<2>(v); v *= scan_shr<4>(v); v *= scan_shr<8>(v);
        const float e   = __expf(-(v * sc));
        const float s   = rcpf(1.f + e);
        const float act = s * sc + off;
        const int ai = __float_as_int(act);
        const float f  = __int_as_float(__builtin_amdgcn_ds_bpermute(i_f, ai));
        const float i_ = __int_as_float(__builtin_amdgcn_ds_bpermute(i_i, ai));
        const float u  = __int_as_float(__builtin_amdgcn_ds_bpermute(i_u, ai));
        const float o  = __int_as_float(__builtin_amdgcn_ds_bpermute(i_o, ai));
        c = f * c + i_ * u;
        const float e2 = __expf(-2.f * c);
        const float th = (1.f - e2) * rcpf(1.f + e2);
        h = o * th;
        return h;
    };

    float c0 = zld(0), c1 = zld(1), c2 = zld(2), c3 = zld(3);
    for (int tl = 0; tl < tc; tl += 4) {
        // prefetch next group (clamped at tail)
        float n0 = zld(tl + 4), n1 = zld(tl + 5), n2 = zld(tl + 6), n3 = zld(tl + 7);
        const float h0 = step(c0);
        const float h1 = step(c1);
        const float h2 = step(c2);
        const float h3 = step(c3);
        if (g == 0) {                     // 4 stores batched per group
            op[0]        = h0;
            op[ostr]     = h1;
            op[ostr * 2] = h2;
            op[ostr * 3] = h3;
        }
        op += ostr * 4;
        c0 = n0; c1 = n1; c2 = n2; c3 = n3;
    }

    if (g == 0) {                         // hx, cx (also chunk carry)
        out[sbase + (size_t)b * NH + k] = h;
        out[sbase + (size_t)BATCH * NH + (size_t)b * NH + k] = c;
    }
}

// ---------------------------------------------------------------------------
// Fallback: original fused kernel (used only if workspace is too small).
// ---------------------------------------------------------------------------
__global__ __launch_bounds__(64, 2) void qlstm_kernel(
    const float* __restrict__ x,
    const float* __restrict__ Wf, const float* __restrict__ bf,
    const float* __restrict__ Wi, const float* __restrict__ bi,
    const float* __restrict__ Wu, const float* __restrict__ bu,
    const float* __restrict__ Wo, const float* __restrict__ bo,
    const float* __restrict__ thf, const float* __restrict__ thi,
    const float* __restrict__ thu, const float* __restrict__ tho,
    float* __restrict__ out)
{
    const int lane = threadIdx.x;
    const int k    = lane & 15;
    const int q    = lane >> 4;
    const int b    = blockIdx.x;

    const float* Wg[4] = {Wf, Wi, Wu, Wo};
    const float* bg[4] = {bf, bi, bu, bo};
    const float* tg[4] = {thf, thi, thu, tho};

    float w[4][32], wh[4][4], bt[4];
#pragma unroll
    for (int g = 0; g < 4; ++g) {
        const float* Wr = Wg[g] + k * COMB;
#pragma unroll
        for (int j = 0; j < 32; ++j) w[g][j] = Wr[q * 32 + j];
#pragma unroll
        for (int kk = 0; kk < 4; ++kk) wh[g][kk] = Wr[DIN + q * 4 + kk];
        bt[g] = bg[g][k] + tg[g][k];
    }

    float h = 0.f, c = 0.f;
    float cvA[32], cvB[32];

    auto xrow = [&](int t) -> const float* {
        return x + ((size_t)t * BATCH + b) * DIN + q * 32;
    };
    auto loadx = [&](float (&cv)[32], const float* p) {
#pragma unroll
        for (int j4 = 0; j4 < 8; ++j4) {
            const float4 v = *(const float4*)(p + j4 * 4);
            cv[j4 * 4 + 0] = v.x; cv[j4 * 4 + 1] = v.y;
            cv[j4 * 4 + 2] = v.z; cv[j4 * 4 + 3] = v.w;
        }
    };

    float* op = out + (size_t)b * NH + k;

    auto step = [&](int t, float (&cv)[32]) {
        float acc[4] = {0.f, 0.f, 0.f, 0.f};
#pragma unroll
        for (int j = 0; j < 32; ++j) {
#pragma unroll
            for (int g = 0; g < 4; ++g) acc[g] += cv[j] * w[g][j];
        }
#pragma unroll
        for (int kk = 0; kk < 4; ++kk) {
            const float hv = __shfl(h, q * 4 + kk, 64);
#pragma unroll
            for (int g = 0; g < 4; ++g) acc[g] += hv * wh[g][kk];
        }
#pragma unroll
        for (int g = 0; g < 4; ++g) {
            acc[g] += __shfl_xor(acc[g], 16, 64);
            acc[g] += __shfl_xor(acc[g], 32, 64);
            acc[g] = __cosf(acc[g] + bt[g]);
        }
#pragma unroll
        for (int g = 0; g < 4; ++g) {
            acc[g] *= scan_shr<1>(acc[g]);
            acc[g] *= scan_shr<2>(acc[g]);
            acc[g] *= scan_shr<4>(acc[g]);
            acc[g] *= scan_shr<8>(acc[g]);
        }
        const float f  = sigmf(acc[0]);
        const float i_ = sigmf(acc[1]);
        const float u  = tanhf_(acc[2]);
        const float o  = sigmf(acc[3]);
        c = f * c + i_ * u;
        h = o * tanhf_(c);
        if (q == 0) *op = h;
        op += (size_t)BATCH * NH;
    };

    loadx(cvA, xrow(0));
    for (int t = 0; t < T_STEPS; t += 2) {
        loadx(cvB, xrow(t + 1));
        step(t, cvA);
        const int tn = (t + 2 < T_STEPS) ? t + 2 : T_STEPS - 1;
        loadx(cvA, xrow(tn));
        step(t + 1, cvB);
    }

    if (q == 0) {
        const size_t base = (size_t)T_STEPS * BATCH * NH;
        out[base + (size_t)b * NH + k] = h;
        out[base + (size_t)BATCH * NH + (size_t)b * NH + k] = c;
    }
}

extern "C" void kernel_launch(void* const* d_in, const int* in_sizes, int n_in,
                              void* d_out, int out_size, void* d_ws, size_t ws_size,
                              hipStream_t stream) {
    const float* x   = (const float*)d_in[0];
    const float* Wf  = (const float*)d_in[1];
    const float* bf  = (const float*)d_in[2];
    const float* Wi  = (const float*)d_in[3];
    const float* bi  = (const float*)d_in[4];
    const float* Wu  = (const float*)d_in[5];
    const float* bu  = (const float*)d_in[6];
    const float* Wo  = (const float*)d_in[7];
    const float* bo  = (const float*)d_in[8];
    const float* thf = (const float*)d_in[9];
    const float* thi = (const float*)d_in[10];
    const float* thu = (const float*)d_in[11];
    const float* tho = (const float*)d_in[12];
    float* out = (float*)d_out;

    // largest T-chunk whose zx slab fits in the workspace (512 -> 256 MiB)
    int Tc = 0;
    const int cand[7] = {512, 256, 128, 64, 32, 16, 8};
    for (int i = 0; i < 7; ++i) {
        if (d_ws && (size_t)cand[i] * BATCH * G64 * sizeof(float) <= ws_size) {
            Tc = cand[i];
            break;
        }
    }
    if (Tc == 0) {   // no usable workspace: fused fallback
        qlstm_kernel<<<dim3(BATCH), dim3(64), 0, stream>>>(
            x, Wf, bf, Wi, bi, Wu, bu, Wo, bo, thf, thi, thu, tho, out);
        return;
    }

    float* zx = (float*)d_ws;
    for (int t0 = 0; t0 < T_STEPS; t0 += Tc) {
        const int tc = (T_STEPS - t0 < Tc) ? (T_STEPS - t0) : Tc;
        zx_kernel<<<dim3(2048), dim3(256), 0, stream>>>(
            x, Wf, bf, Wi, bi, Wu, bu, Wo, bo, thf, thi, thu, tho, zx, t0, tc);
        rec_kernel<<<dim3(BATCH / 4), dim3(256), 0, stream>>>(
            zx, Wf, Wi, Wu, Wo, out, t0, tc);
    }
}